// Round 10
// baseline (706.063 us; speedup 1.0000x reference)
//
#include <hip/hip_runtime.h>

typedef __bf16 bf16x8 __attribute__((ext_vector_type(8)));
typedef float  f32x4  __attribute__((ext_vector_type(4)));

#define ND   64
#define HD   128
#define NSEG 1024
#define PROBE_REPS 8

__device__ __forceinline__ int lower_bound_i(const int* __restrict__ a, int n, int v) {
  int lo = 0, hi = n;
  while (lo < hi) { int m = (lo + hi) >> 1; if (a[m] < v) lo = m + 1; else hi = m; }
  return lo;
}

// Diagnostic: pure-read BW ceiling probe (grid-stride f32x4 sweep of x, 8x).
// Sized to be the slowest dispatch -> its 5 graph-replays own rocprof top-5,
// so its hbm_gbps is a direct measurement of the achievable READ bandwidth.
__global__ __launch_bounds__(256) void k_read_probe(const float* __restrict__ x,
                                                    long long n4,
                                                    float* __restrict__ scratch) {
  const long long tid    = (long long)blockIdx.x * 256 + threadIdx.x;
  const long long stride = (long long)gridDim.x * 256;
  float acc = 0.f;
  for (int r = 0; r < PROBE_REPS; ++r) {
    #pragma unroll 4
    for (long long i = tid; i < n4; i += stride) {
      f32x4 v = *(const f32x4*)(x + 4 * i);
      acc += (v[0] + v[1]) + (v[2] + v[3]);
    }
  }
  if (acc == 1234.567f) scratch[0] = acc;   // keep loads live; ~never taken
}

// K0: seg_start[s] = first row of segment s (xb sorted); seg_start[NSEG] = n.
__global__ __launch_bounds__(128) void k_bounds(const int* __restrict__ xb, int n,
                                                int* __restrict__ ss) {
  const int s = blockIdx.x * 128 + threadIdx.x;
  if (s <= NSEG) ss[s] = lower_bound_i(xb, n, s);
}

// K1 (fused): per segment: segment-sum of relu(x@W1+b1) (R9 main loop:
// 8 waves, lean regs, no atomics) -> mean -> @W2+b2 -> relu(@W3+b3) -> @W4+b4
// all inside the block; out written directly. No sums round-trip, no k_rho.
// A frag: lane=(l16 row, lgrp), k = h*32 + lgrp*8 + e. B frag: same k map.
// D frag: col = lane&15, row = 4*(lane>>4)+reg  (HW-verified R1-R9).
__global__ __launch_bounds__(512, 8) void k_phi(const float* __restrict__ x,
                                                const int* __restrict__ ss,
                                                const float* __restrict__ W1,
                                                const float* __restrict__ b1,
                                                const float* __restrict__ W2,
                                                const float* __restrict__ b2,
                                                const float* __restrict__ W3,
                                                const float* __restrict__ b3,
                                                const float* __restrict__ W4,
                                                const float* __restrict__ b4,
                                                float* __restrict__ out) {
  __shared__ __align__(16) char ldsW[16 * 1024];
  __shared__ float ldsB[HD];
  __shared__ float ldsR[8 * HD];
  __shared__ float ldsE[2 * HD];
  const int lane = threadIdx.x & 63;
  const int wave = threadIdx.x >> 6;          // 0..7
  const int l16  = lane & 15;
  const int lgrp = lane >> 4;
  const int s    = blockIdx.x;

  const int r0   = ss[s];
  const int rows = ss[s + 1] - r0;

  // stage W1 fragments into LDS: frag f = kt*8+ct at [f][lane][16B]; 2 per wave
  #pragma unroll
  for (int i = 0; i < 2; ++i) {
    const int f = wave + i * 8, kt = f >> 3, ct = f & 7;
    bf16x8 fr;
    #pragma unroll
    for (int e = 0; e < 8; ++e)
      fr[e] = (__bf16)W1[(kt * 32 + lgrp * 8 + e) * HD + ct * 16 + l16];
    *(bf16x8*)(&ldsW[f * 1024 + lane * 16]) = fr;
  }
  if (threadIdx.x < HD) ldsB[threadIdx.x] = b1[threadIdx.x];
  __syncthreads();

  float seg_acc[8] = {0.f, 0.f, 0.f, 0.f, 0.f, 0.f, 0.f, 0.f};
  const int tiles = (rows + 15) >> 4;
  const float* xb0 = x + (size_t)r0 * ND;

  for (int t = wave; t < tiles; t += 8) {
    const int rr = min(t * 16 + l16, rows - 1);
    const float* p = xb0 + (size_t)rr * ND + lgrp * 8;
    f32x4 v0 = *(const f32x4*)(p);
    f32x4 v1 = *(const f32x4*)(p + 4);
    f32x4 v2 = *(const f32x4*)(p + 32);
    f32x4 v3 = *(const f32x4*)(p + 36);
    bf16x8 a0, a1;
    #pragma unroll
    for (int e = 0; e < 4; ++e) {
      a0[e] = (__bf16)v0[e]; a0[e + 4] = (__bf16)v1[e];
      a1[e] = (__bf16)v2[e]; a1[e + 4] = (__bf16)v3[e];
    }
    int lb = lane * 16;
    asm volatile("" : "+v"(lb));    // defeat LICM: frag reads stay in-loop
    const int lim = rows - t * 16;  // >=16 for all but the last tile

    if (lim >= 16) {
      #pragma unroll
      for (int ct = 0; ct < 8; ++ct) {
        const float bias = ldsB[ct * 16 + l16];
        f32x4 c; c[0] = c[1] = c[2] = c[3] = bias;
        bf16x8 f0 = *(const bf16x8*)(&ldsW[ct * 1024 + lb]);
        bf16x8 f1 = *(const bf16x8*)(&ldsW[(8 + ct) * 1024 + lb]);
        c = __builtin_amdgcn_mfma_f32_16x16x32_bf16(a0, f0, c, 0, 0, 0);
        c = __builtin_amdgcn_mfma_f32_16x16x32_bf16(a1, f1, c, 0, 0, 0);
        seg_acc[ct] += (fmaxf(c[0], 0.f) + fmaxf(c[1], 0.f)) +
                       (fmaxf(c[2], 0.f) + fmaxf(c[3], 0.f));
      }
    } else {
      #pragma unroll
      for (int ct = 0; ct < 8; ++ct) {
        const float bias = ldsB[ct * 16 + l16];
        f32x4 c; c[0] = c[1] = c[2] = c[3] = bias;
        bf16x8 f0 = *(const bf16x8*)(&ldsW[ct * 1024 + lb]);
        bf16x8 f1 = *(const bf16x8*)(&ldsW[(8 + ct) * 1024 + lb]);
        c = __builtin_amdgcn_mfma_f32_16x16x32_bf16(a0, f0, c, 0, 0, 0);
        c = __builtin_amdgcn_mfma_f32_16x16x32_bf16(a1, f1, c, 0, 0, 0);
        #pragma unroll
        for (int i = 0; i < 4; ++i)
          seg_acc[ct] += (4 * lgrp + i < lim) ? fmaxf(c[i], 0.f) : 0.f;
      }
    }
  }

  // cross-rowgroup then cross-wave reduce (into LDS; no global sums)
  #pragma unroll
  for (int ct = 0; ct < 8; ++ct) {
    float v = seg_acc[ct];
    v += __shfl_xor(v, 16);
    v += __shfl_xor(v, 32);
    if (lane < 16) ldsR[wave * HD + ct * 16 + l16] = v;
  }
  __syncthreads();

  // ---- fused rho: mean -> @W2+b2 -> relu(@W3+b3) -> @W4+b4 ----
  const int j = threadIdx.x;
  if (j < HD) {
    float r = 0.f;
    #pragma unroll
    for (int w = 0; w < 8; ++w) r += ldsR[w * HD + j];
    ldsE[j] = r / fmaxf((float)rows, 1.f);          // mean of relu-activations
  }
  __syncthreads();
  if (j < HD) {
    float hid = b2[j];
    #pragma unroll 8
    for (int k = 0; k < HD; ++k) hid = fmaf(ldsE[k], W2[k * HD + j], hid);
    if (rows == 0) hid = 0.f;     // reference: empty segment -> hid = 0 (not b2)
    ldsE[HD + j] = hid;
  }
  __syncthreads();
  if (j < HD) {
    float t2 = b3[j];
    #pragma unroll 8
    for (int k = 0; k < HD; ++k) t2 = fmaf(ldsE[HD + k], W3[k * HD + j], t2);
    ldsE[j] = fmaxf(t2, 0.f);
  }
  __syncthreads();
  if (j < 16) {
    float o = b4[j];
    #pragma unroll 8
    for (int k = 0; k < HD; ++k) o = fmaf(ldsE[k], W4[k * 16 + j], o);
    out[s * 16 + j] = o;
  }
}

extern "C" void kernel_launch(void* const* d_in, const int* in_sizes, int n_in,
                              void* d_out, int out_size, void* d_ws, size_t ws_size,
                              hipStream_t stream) {
  const float* x  = (const float*)d_in[0];
  const int*   xb = (const int*)  d_in[1];
  const float* W1 = (const float*)d_in[2];
  const float* b1 = (const float*)d_in[3];
  const float* W2 = (const float*)d_in[4];
  const float* b2 = (const float*)d_in[5];
  const float* W3 = (const float*)d_in[6];
  const float* b3 = (const float*)d_in[7];
  const float* W4 = (const float*)d_in[8];
  const float* b4 = (const float*)d_in[9];
  float* out = (float*)d_out;
  const int n = in_sizes[1];

  int*   ss      = (int*)d_ws;                 // [NSEG+1]
  float* scratch = (float*)d_ws + 2048;        // probe keep-alive slot

  // diagnostic read-ceiling probe (sacrificial this round)
  const long long n4 = (long long)n * ND / 4;
  k_read_probe<<<2048, 256, 0, stream>>>(x, n4, scratch);

  k_bounds<<<(NSEG + 1 + 127) / 128, 128, 0, stream>>>(xb, n, ss);
  k_phi<<<NSEG, 512, 0, stream>>>(x, ss, W1, b1, W2, b2, W3, b3, W4, b4, out);
}

// Round 11
// 114.614 us; speedup vs baseline: 6.1604x; 6.1604x over previous
//
#include <hip/hip_runtime.h>

typedef __bf16 bf16x8 __attribute__((ext_vector_type(8)));
typedef float  f32x4  __attribute__((ext_vector_type(4)));

#define ND   64
#define HD   128
#define NSEG 1024

__device__ __forceinline__ int lower_bound_i(const int* __restrict__ a, int n, int v) {
  int lo = 0, hi = n;
  while (lo < hi) { int m = (lo + hi) >> 1; if (a[m] < v) lo = m + 1; else hi = m; }
  return lo;
}

// K0: seg_start[s] = first row of segment s (xb sorted); seg_start[NSEG] = n.
__global__ __launch_bounds__(128) void k_bounds(const int* __restrict__ xb, int n,
                                                int* __restrict__ ss) {
  const int s = blockIdx.x * 128 + threadIdx.x;
  if (s <= NSEG) ss[s] = lower_bound_i(xb, n, s);
}

// K1 (fused): per segment: segment-sum of relu(x@W1+b1) (8 waves, lean regs,
// no atomics) -> mean -> @W2+b2 -> relu(@W3+b3) -> @W4+b4, out written direct.
// x loads are NONTEMPORAL: x is read exactly once per call, so L3 allocation
// is pure overhead; if the ~4.3 TB/s plateau is the L3 miss/fill path, nt
// streaming should lift it toward the one-directional HBM rate (~6.5, cf.
// fills at 6.6-6.9). W1/b*/W* loads stay cached (hot, reused by 1024 blocks).
// A frag: lane=(l16 row, lgrp), k = h*32 + lgrp*8 + e. B frag: same k map.
// D frag: col = lane&15, row = 4*(lane>>4)+reg  (HW-verified R1-R10).
__global__ __launch_bounds__(512, 8) void k_phi(const float* __restrict__ x,
                                                const int* __restrict__ ss,
                                                const float* __restrict__ W1,
                                                const float* __restrict__ b1,
                                                const float* __restrict__ W2,
                                                const float* __restrict__ b2,
                                                const float* __restrict__ W3,
                                                const float* __restrict__ b3,
                                                const float* __restrict__ W4,
                                                const float* __restrict__ b4,
                                                float* __restrict__ out) {
  __shared__ __align__(16) char ldsW[16 * 1024];
  __shared__ float ldsB[HD];
  __shared__ float ldsR[8 * HD];
  __shared__ float ldsE[2 * HD];
  const int lane = threadIdx.x & 63;
  const int wave = threadIdx.x >> 6;          // 0..7
  const int l16  = lane & 15;
  const int lgrp = lane >> 4;
  const int s    = blockIdx.x;

  const int r0   = ss[s];
  const int rows = ss[s + 1] - r0;

  // stage W1 fragments into LDS: frag f = kt*8+ct at [f][lane][16B]; 2 per wave
  #pragma unroll
  for (int i = 0; i < 2; ++i) {
    const int f = wave + i * 8, kt = f >> 3, ct = f & 7;
    bf16x8 fr;
    #pragma unroll
    for (int e = 0; e < 8; ++e)
      fr[e] = (__bf16)W1[(kt * 32 + lgrp * 8 + e) * HD + ct * 16 + l16];
    *(bf16x8*)(&ldsW[f * 1024 + lane * 16]) = fr;
  }
  if (threadIdx.x < HD) ldsB[threadIdx.x] = b1[threadIdx.x];
  __syncthreads();

  float seg_acc[8] = {0.f, 0.f, 0.f, 0.f, 0.f, 0.f, 0.f, 0.f};
  const int tiles = (rows + 15) >> 4;
  const float* xb0 = x + (size_t)r0 * ND;

  for (int t = wave; t < tiles; t += 8) {
    const int rr = min(t * 16 + l16, rows - 1);
    const float* p = xb0 + (size_t)rr * ND + lgrp * 8;
    f32x4 v0 = __builtin_nontemporal_load((const f32x4*)(p));
    f32x4 v1 = __builtin_nontemporal_load((const f32x4*)(p + 4));
    f32x4 v2 = __builtin_nontemporal_load((const f32x4*)(p + 32));
    f32x4 v3 = __builtin_nontemporal_load((const f32x4*)(p + 36));
    bf16x8 a0, a1;
    #pragma unroll
    for (int e = 0; e < 4; ++e) {
      a0[e] = (__bf16)v0[e]; a0[e + 4] = (__bf16)v1[e];
      a1[e] = (__bf16)v2[e]; a1[e + 4] = (__bf16)v3[e];
    }
    int lb = lane * 16;
    asm volatile("" : "+v"(lb));    // defeat LICM: frag reads stay in-loop
    const int lim = rows - t * 16;  // >=16 for all but the last tile

    if (lim >= 16) {
      #pragma unroll
      for (int ct = 0; ct < 8; ++ct) {
        const float bias = ldsB[ct * 16 + l16];
        f32x4 c; c[0] = c[1] = c[2] = c[3] = bias;
        bf16x8 f0 = *(const bf16x8*)(&ldsW[ct * 1024 + lb]);
        bf16x8 f1 = *(const bf16x8*)(&ldsW[(8 + ct) * 1024 + lb]);
        c = __builtin_amdgcn_mfma_f32_16x16x32_bf16(a0, f0, c, 0, 0, 0);
        c = __builtin_amdgcn_mfma_f32_16x16x32_bf16(a1, f1, c, 0, 0, 0);
        seg_acc[ct] += (fmaxf(c[0], 0.f) + fmaxf(c[1], 0.f)) +
                       (fmaxf(c[2], 0.f) + fmaxf(c[3], 0.f));
      }
    } else {
      #pragma unroll
      for (int ct = 0; ct < 8; ++ct) {
        const float bias = ldsB[ct * 16 + l16];
        f32x4 c; c[0] = c[1] = c[2] = c[3] = bias;
        bf16x8 f0 = *(const bf16x8*)(&ldsW[ct * 1024 + lb]);
        bf16x8 f1 = *(const bf16x8*)(&ldsW[(8 + ct) * 1024 + lb]);
        c = __builtin_amdgcn_mfma_f32_16x16x32_bf16(a0, f0, c, 0, 0, 0);
        c = __builtin_amdgcn_mfma_f32_16x16x32_bf16(a1, f1, c, 0, 0, 0);
        #pragma unroll
        for (int i = 0; i < 4; ++i)
          seg_acc[ct] += (4 * lgrp + i < lim) ? fmaxf(c[i], 0.f) : 0.f;
      }
    }
  }

  // cross-rowgroup then cross-wave reduce (into LDS; no global sums)
  #pragma unroll
  for (int ct = 0; ct < 8; ++ct) {
    float v = seg_acc[ct];
    v += __shfl_xor(v, 16);
    v += __shfl_xor(v, 32);
    if (lane < 16) ldsR[wave * HD + ct * 16 + l16] = v;
  }
  __syncthreads();

  // ---- fused rho: mean -> @W2+b2 -> relu(@W3+b3) -> @W4+b4 ----
  const int j = threadIdx.x;
  if (j < HD) {
    float r = 0.f;
    #pragma unroll
    for (int w = 0; w < 8; ++w) r += ldsR[w * HD + j];
    ldsE[j] = r / fmaxf((float)rows, 1.f);          // mean of relu-activations
  }
  __syncthreads();
  if (j < HD) {
    float hid = b2[j];
    #pragma unroll 8
    for (int k = 0; k < HD; ++k) hid = fmaf(ldsE[k], W2[k * HD + j], hid);
    if (rows == 0) hid = 0.f;     // reference: empty segment -> hid = 0 (not b2)
    ldsE[HD + j] = hid;
  }
  __syncthreads();
  if (j < HD) {
    float t2 = b3[j];
    #pragma unroll 8
    for (int k = 0; k < HD; ++k) t2 = fmaf(ldsE[HD + k], W3[k * HD + j], t2);
    ldsE[j] = fmaxf(t2, 0.f);
  }
  __syncthreads();
  if (j < 16) {
    float o = b4[j];
    #pragma unroll 8
    for (int k = 0; k < HD; ++k) o = fmaf(ldsE[k], W4[k * 16 + j], o);
    out[s * 16 + j] = o;
  }
}

extern "C" void kernel_launch(void* const* d_in, const int* in_sizes, int n_in,
                              void* d_out, int out_size, void* d_ws, size_t ws_size,
                              hipStream_t stream) {
  const float* x  = (const float*)d_in[0];
  const int*   xb = (const int*)  d_in[1];
  const float* W1 = (const float*)d_in[2];
  const float* b1 = (const float*)d_in[3];
  const float* W2 = (const float*)d_in[4];
  const float* b2 = (const float*)d_in[5];
  const float* W3 = (const float*)d_in[6];
  const float* b3 = (const float*)d_in[7];
  const float* W4 = (const float*)d_in[8];
  const float* b4 = (const float*)d_in[9];
  float* out = (float*)d_out;
  const int n = in_sizes[1];

  int* ss = (int*)d_ws;                 // [NSEG+1]

  k_bounds<<<(NSEG + 1 + 127) / 128, 128, 0, stream>>>(xb, n, ss);
  k_phi<<<NSEG, 512, 0, stream>>>(x, ss, W1, b1, W2, b2, W3, b3, W4, b4, out);
}

// Round 12
// 112.387 us; speedup vs baseline: 6.2824x; 1.0198x over previous
//
#include <hip/hip_runtime.h>

typedef __bf16 bf16x8 __attribute__((ext_vector_type(8)));
typedef float  f32x4  __attribute__((ext_vector_type(4)));

#define ND   64
#define HD   128
#define NSEG 1024

__device__ __forceinline__ int lower_bound_i(const int* __restrict__ a, int n, int v) {
  int lo = 0, hi = n;
  while (lo < hi) { int m = (lo + hi) >> 1; if (a[m] < v) lo = m + 1; else hi = m; }
  return lo;
}

// Single fused kernel: one block per segment.
//  prologue: threads 0/1 binary-search this segment's row range (concurrent
//            with W1 fragment staging by the other threads, one barrier)
//  main:     segment-sum of relu(x@W1+b1), 8 waves, NT x-loads (x is
//            single-use; bypassing L3 allocation lifted 4.3->4.8 TB/s in R11),
//            lean regs, no atomics
//  epilogue: mean -> @W2+b2 -> relu(@W3+b3) -> @W4+b4 -> out (direct)
// A frag: lane=(l16 row, lgrp), k = h*32 + lgrp*8 + e. B frag: same k map.
// D frag: col = lane&15, row = 4*(lane>>4)+reg  (HW-verified R1-R11).
__global__ __launch_bounds__(512, 8) void k_deepset(const float* __restrict__ x,
                                                    const int* __restrict__ xb, int n,
                                                    const float* __restrict__ W1,
                                                    const float* __restrict__ b1,
                                                    const float* __restrict__ W2,
                                                    const float* __restrict__ b2,
                                                    const float* __restrict__ W3,
                                                    const float* __restrict__ b3,
                                                    const float* __restrict__ W4,
                                                    const float* __restrict__ b4,
                                                    float* __restrict__ out) {
  __shared__ __align__(16) char ldsW[16 * 1024];
  __shared__ float ldsB[HD];
  __shared__ float ldsR[8 * HD];
  __shared__ float ldsE[2 * HD];
  __shared__ int   sB[2];
  const int lane = threadIdx.x & 63;
  const int wave = threadIdx.x >> 6;          // 0..7
  const int l16  = lane & 15;
  const int lgrp = lane >> 4;
  const int s    = blockIdx.x;

  // segment bounds: 2 binary searches, overlapped with W1 staging below
  if (threadIdx.x < 2) sB[threadIdx.x] = lower_bound_i(xb, n, s + threadIdx.x);

  // stage W1 fragments into LDS: frag f = kt*8+ct at [f][lane][16B]; 2 per wave
  #pragma unroll
  for (int i = 0; i < 2; ++i) {
    const int f = wave + i * 8, kt = f >> 3, ct = f & 7;
    bf16x8 fr;
    #pragma unroll
    for (int e = 0; e < 8; ++e)
      fr[e] = (__bf16)W1[(kt * 32 + lgrp * 8 + e) * HD + ct * 16 + l16];
    *(bf16x8*)(&ldsW[f * 1024 + lane * 16]) = fr;
  }
  if (threadIdx.x < HD) ldsB[threadIdx.x] = b1[threadIdx.x];
  __syncthreads();

  const int r0   = sB[0];
  const int rows = sB[1] - r0;

  float seg_acc[8] = {0.f, 0.f, 0.f, 0.f, 0.f, 0.f, 0.f, 0.f};
  const int tiles = (rows + 15) >> 4;
  const float* xb0 = x + (size_t)r0 * ND;

  for (int t = wave; t < tiles; t += 8) {
    const int rr = min(t * 16 + l16, rows - 1);
    const float* p = xb0 + (size_t)rr * ND + lgrp * 8;
    f32x4 v0 = __builtin_nontemporal_load((const f32x4*)(p));
    f32x4 v1 = __builtin_nontemporal_load((const f32x4*)(p + 4));
    f32x4 v2 = __builtin_nontemporal_load((const f32x4*)(p + 32));
    f32x4 v3 = __builtin_nontemporal_load((const f32x4*)(p + 36));
    bf16x8 a0, a1;
    #pragma unroll
    for (int e = 0; e < 4; ++e) {
      a0[e] = (__bf16)v0[e]; a0[e + 4] = (__bf16)v1[e];
      a1[e] = (__bf16)v2[e]; a1[e + 4] = (__bf16)v3[e];
    }
    int lb = lane * 16;
    asm volatile("" : "+v"(lb));    // defeat LICM: frag reads stay in-loop
    const int lim = rows - t * 16;  // >=16 for all but the last tile

    if (lim >= 16) {
      #pragma unroll
      for (int ct = 0; ct < 8; ++ct) {
        const float bias = ldsB[ct * 16 + l16];
        f32x4 c; c[0] = c[1] = c[2] = c[3] = bias;
        bf16x8 f0 = *(const bf16x8*)(&ldsW[ct * 1024 + lb]);
        bf16x8 f1 = *(const bf16x8*)(&ldsW[(8 + ct) * 1024 + lb]);
        c = __builtin_amdgcn_mfma_f32_16x16x32_bf16(a0, f0, c, 0, 0, 0);
        c = __builtin_amdgcn_mfma_f32_16x16x32_bf16(a1, f1, c, 0, 0, 0);
        seg_acc[ct] += (fmaxf(c[0], 0.f) + fmaxf(c[1], 0.f)) +
                       (fmaxf(c[2], 0.f) + fmaxf(c[3], 0.f));
      }
    } else {
      #pragma unroll
      for (int ct = 0; ct < 8; ++ct) {
        const float bias = ldsB[ct * 16 + l16];
        f32x4 c; c[0] = c[1] = c[2] = c[3] = bias;
        bf16x8 f0 = *(const bf16x8*)(&ldsW[ct * 1024 + lb]);
        bf16x8 f1 = *(const bf16x8*)(&ldsW[(8 + ct) * 1024 + lb]);
        c = __builtin_amdgcn_mfma_f32_16x16x32_bf16(a0, f0, c, 0, 0, 0);
        c = __builtin_amdgcn_mfma_f32_16x16x32_bf16(a1, f1, c, 0, 0, 0);
        #pragma unroll
        for (int i = 0; i < 4; ++i)
          seg_acc[ct] += (4 * lgrp + i < lim) ? fmaxf(c[i], 0.f) : 0.f;
      }
    }
  }

  // cross-rowgroup then cross-wave reduce (into LDS; no global sums)
  #pragma unroll
  for (int ct = 0; ct < 8; ++ct) {
    float v = seg_acc[ct];
    v += __shfl_xor(v, 16);
    v += __shfl_xor(v, 32);
    if (lane < 16) ldsR[wave * HD + ct * 16 + l16] = v;
  }
  __syncthreads();

  // ---- fused rho: mean -> @W2+b2 -> relu(@W3+b3) -> @W4+b4 ----
  const int j = threadIdx.x;
  if (j < HD) {
    float r = 0.f;
    #pragma unroll
    for (int w = 0; w < 8; ++w) r += ldsR[w * HD + j];
    ldsE[j] = r / fmaxf((float)rows, 1.f);          // mean of relu-activations
  }
  __syncthreads();
  if (j < HD) {
    float hid = b2[j];
    #pragma unroll 8
    for (int k = 0; k < HD; ++k) hid = fmaf(ldsE[k], W2[k * HD + j], hid);
    if (rows == 0) hid = 0.f;     // reference: empty segment -> hid = 0 (not b2)
    ldsE[HD + j] = hid;
  }
  __syncthreads();
  if (j < HD) {
    float t2 = b3[j];
    #pragma unroll 8
    for (int k = 0; k < HD; ++k) t2 = fmaf(ldsE[HD + k], W3[k * HD + j], t2);
    ldsE[j] = fmaxf(t2, 0.f);
  }
  __syncthreads();
  if (j < 16) {
    float o = b4[j];
    #pragma unroll 8
    for (int k = 0; k < HD; ++k) o = fmaf(ldsE[k], W4[k * 16 + j], o);
    out[s * 16 + j] = o;
  }
}

extern "C" void kernel_launch(void* const* d_in, const int* in_sizes, int n_in,
                              void* d_out, int out_size, void* d_ws, size_t ws_size,
                              hipStream_t stream) {
  const float* x  = (const float*)d_in[0];
  const int*   xb = (const int*)  d_in[1];
  const float* W1 = (const float*)d_in[2];
  const float* b1 = (const float*)d_in[3];
  const float* W2 = (const float*)d_in[4];
  const float* b2 = (const float*)d_in[5];
  const float* W3 = (const float*)d_in[6];
  const float* b3 = (const float*)d_in[7];
  const float* W4 = (const float*)d_in[8];
  const float* b4 = (const float*)d_in[9];
  float* out = (float*)d_out;
  const int n = in_sizes[1];

  k_deepset<<<NSEG, 512, 0, stream>>>(x, xb, n, W1, b1, W2, b2, W3, b3, W4, b4, out);
}

// Round 13
// 104.290 us; speedup vs baseline: 6.7702x; 1.0776x over previous
//
#include <hip/hip_runtime.h>

typedef __bf16 bf16x8 __attribute__((ext_vector_type(8)));
typedef float  f32x4  __attribute__((ext_vector_type(4)));

#define ND   64
#define HD   128
#define NSEG 1024

__device__ __forceinline__ int lower_bound_i(const int* __restrict__ a, int n, int v) {
  int lo = 0, hi = n;
  while (lo < hi) { int m = (lo + hi) >> 1; if (a[m] < v) lo = m + 1; else hi = m; }
  return lo;
}

// Single fused kernel, one block per segment, 8 waves.
// x path: 4 fully-contiguous 1KB NT load instructions per 16-row tile (every
// 64B line fully covered by one instruction -> clean NT sector requests),
// then per-wave LDS transit (granule-XOR swizzle, verified in R8) to rebuild
// MFMA A-fragments. NT because x is single-use (R11: +23% from bypassing L3
// allocation). W1 frags in LDS; no atomics; fused rho epilogue.
// A frag: lane=(l16 row, lgrp), k = h*32 + lgrp*8 + e. B frag: same k map.
// D frag: col = lane&15, row = 4*(lane>>4)+reg  (HW-verified R1-R12).
__global__ __launch_bounds__(512, 6) void k_deepset(const float* __restrict__ x,
                                                    const int* __restrict__ xb, int n,
                                                    const float* __restrict__ W1,
                                                    const float* __restrict__ b1,
                                                    const float* __restrict__ W2,
                                                    const float* __restrict__ b2,
                                                    const float* __restrict__ W3,
                                                    const float* __restrict__ b3,
                                                    const float* __restrict__ W4,
                                                    const float* __restrict__ b4,
                                                    float* __restrict__ out) {
  __shared__ __align__(16) char  ldsW[16 * 1024];
  __shared__ __align__(16) char  ldsX[8][4096];   // per-wave transit
  __shared__ float ldsB[HD];
  __shared__ float ldsR[8 * HD];
  __shared__ int   sB[2];
  float* ldsE = ldsR;   // aliased; access patterns disjoint across barriers
  const int lane = threadIdx.x & 63;
  const int wave = threadIdx.x >> 6;          // 0..7
  const int l16  = lane & 15;
  const int lgrp = lane >> 4;
  const int s    = blockIdx.x;

  // segment bounds overlapped with W1 staging
  if (threadIdx.x < 2) sB[threadIdx.x] = lower_bound_i(xb, n, s + threadIdx.x);

  #pragma unroll
  for (int i = 0; i < 2; ++i) {
    const int f = wave + i * 8, kt = f >> 3, ct = f & 7;
    bf16x8 fr;
    #pragma unroll
    for (int e = 0; e < 8; ++e)
      fr[e] = (__bf16)W1[(kt * 32 + lgrp * 8 + e) * HD + ct * 16 + l16];
    *(bf16x8*)(&ldsW[f * 1024 + lane * 16]) = fr;
  }
  if (threadIdx.x < HD) ldsB[threadIdx.x] = b1[threadIdx.x];
  __syncthreads();

  const int r0   = sB[0];
  const int rows = sB[1] - r0;

  // transit addresses (R8-verified). write: instr j holds row rl=4j+lgrp,
  // granule l16, stored at granule l16^(rl&7). read: lane's row l16, true
  // granule g, at g^(l16&7).
  char* myX = &ldsX[wave][0];
  int waddr[4];
  #pragma unroll
  for (int j = 0; j < 4; ++j) {
    const int rl = 4 * j + lgrp;
    waddr[j] = rl * 256 + ((l16 ^ (rl & 7)) << 4);
  }
  const int sw  = l16 & 7;
  const int ra0 = l16 * 256 + (((2 * lgrp)     ^ sw) << 4);
  const int ra1 = l16 * 256 + (((2 * lgrp + 1) ^ sw) << 4);
  const int ra2 = l16 * 256 + (((8 + 2 * lgrp) ^ sw) << 4);
  const int ra3 = l16 * 256 + (((9 + 2 * lgrp) ^ sw) << 4);

  float seg_acc[8] = {0.f, 0.f, 0.f, 0.f, 0.f, 0.f, 0.f, 0.f};
  const int tiles = (rows + 15) >> 4;
  const float* xb0 = x + (size_t)r0 * ND;
  const int g4 = l16 * 4;

  for (int t = wave; t < tiles; t += 8) {
    const int rb = t * 16 + lgrp;
    f32x4 v0 = __builtin_nontemporal_load(
        (const f32x4*)(xb0 + (size_t)min(rb,      rows - 1) * ND + g4));
    f32x4 v1 = __builtin_nontemporal_load(
        (const f32x4*)(xb0 + (size_t)min(rb + 4,  rows - 1) * ND + g4));
    f32x4 v2 = __builtin_nontemporal_load(
        (const f32x4*)(xb0 + (size_t)min(rb + 8,  rows - 1) * ND + g4));
    f32x4 v3 = __builtin_nontemporal_load(
        (const f32x4*)(xb0 + (size_t)min(rb + 12, rows - 1) * ND + g4));

    // transit: regs -> LDS (swizzled) -> fragment-order regs
    *(f32x4*)(myX + waddr[0]) = v0;
    *(f32x4*)(myX + waddr[1]) = v1;
    *(f32x4*)(myX + waddr[2]) = v2;
    *(f32x4*)(myX + waddr[3]) = v3;
    f32x4 q00 = *(const f32x4*)(myX + ra0);
    f32x4 q01 = *(const f32x4*)(myX + ra1);
    f32x4 q10 = *(const f32x4*)(myX + ra2);
    f32x4 q11 = *(const f32x4*)(myX + ra3);

    bf16x8 a0, a1;
    #pragma unroll
    for (int e = 0; e < 4; ++e) {
      a0[e] = (__bf16)q00[e]; a0[e + 4] = (__bf16)q01[e];
      a1[e] = (__bf16)q10[e]; a1[e + 4] = (__bf16)q11[e];
    }
    int lb = lane * 16;
    asm volatile("" : "+v"(lb));    // defeat LICM: frag reads stay in-loop
    const int lim = rows - t * 16;  // >=16 for all but the last tile

    if (lim >= 16) {
      #pragma unroll
      for (int ct = 0; ct < 8; ++ct) {
        const float bias = ldsB[ct * 16 + l16];
        f32x4 c; c[0] = c[1] = c[2] = c[3] = bias;
        bf16x8 f0 = *(const bf16x8*)(&ldsW[ct * 1024 + lb]);
        bf16x8 f1 = *(const bf16x8*)(&ldsW[(8 + ct) * 1024 + lb]);
        c = __builtin_amdgcn_mfma_f32_16x16x32_bf16(a0, f0, c, 0, 0, 0);
        c = __builtin_amdgcn_mfma_f32_16x16x32_bf16(a1, f1, c, 0, 0, 0);
        seg_acc[ct] += (fmaxf(c[0], 0.f) + fmaxf(c[1], 0.f)) +
                       (fmaxf(c[2], 0.f) + fmaxf(c[3], 0.f));
      }
    } else {
      #pragma unroll
      for (int ct = 0; ct < 8; ++ct) {
        const float bias = ldsB[ct * 16 + l16];
        f32x4 c; c[0] = c[1] = c[2] = c[3] = bias;
        bf16x8 f0 = *(const bf16x8*)(&ldsW[ct * 1024 + lb]);
        bf16x8 f1 = *(const bf16x8*)(&ldsW[(8 + ct) * 1024 + lb]);
        c = __builtin_amdgcn_mfma_f32_16x16x32_bf16(a0, f0, c, 0, 0, 0);
        c = __builtin_amdgcn_mfma_f32_16x16x32_bf16(a1, f1, c, 0, 0, 0);
        #pragma unroll
        for (int i = 0; i < 4; ++i)
          seg_acc[ct] += (4 * lgrp + i < lim) ? fmaxf(c[i], 0.f) : 0.f;
      }
    }
  }

  // cross-rowgroup then cross-wave reduce (into LDS; no global sums)
  #pragma unroll
  for (int ct = 0; ct < 8; ++ct) {
    float v = seg_acc[ct];
    v += __shfl_xor(v, 16);
    v += __shfl_xor(v, 32);
    if (lane < 16) ldsR[wave * HD + ct * 16 + l16] = v;
  }
  __syncthreads();

  // ---- fused rho: mean -> @W2+b2 -> relu(@W3+b3) -> @W4+b4 ----
  const int j = threadIdx.x;
  if (j < HD) {
    float r = 0.f;
    #pragma unroll
    for (int w = 0; w < 8; ++w) r += ldsR[w * HD + j];
    // write aliases ldsR[j]; thread j is the only reader of indices == j mod HD
    ldsE[j] = r / fmaxf((float)rows, 1.f);
  }
  __syncthreads();
  if (j < HD) {
    float hid = b2[j];
    #pragma unroll 8
    for (int k = 0; k < HD; ++k) hid = fmaf(ldsE[k], W2[k * HD + j], hid);
    if (rows == 0) hid = 0.f;     // reference: empty segment -> hid = 0 (not b2)
    ldsE[HD + j] = hid;
  }
  __syncthreads();
  if (j < HD) {
    float t2 = b3[j];
    #pragma unroll 8
    for (int k = 0; k < HD; ++k) t2 = fmaf(ldsE[HD + k], W3[k * HD + j], t2);
    float tr = fmaxf(t2, 0.f);
    __syncthreads();              // all reads of ldsE[HD+*] done before overwrite
    ldsE[j] = tr;
  } else {
    __syncthreads();
  }
  __syncthreads();
  if (j < 16) {
    float o = b4[j];
    #pragma unroll 8
    for (int k = 0; k < HD; ++k) o = fmaf(ldsE[k], W4[k * 16 + j], o);
    out[s * 16 + j] = o;
  }
}

extern "C" void kernel_launch(void* const* d_in, const int* in_sizes, int n_in,
                              void* d_out, int out_size, void* d_ws, size_t ws_size,
                              hipStream_t stream) {
  const float* x  = (const float*)d_in[0];
  const int*   xb = (const int*)  d_in[1];
  const float* W1 = (const float*)d_in[2];
  const float* b1 = (const float*)d_in[3];
  const float* W2 = (const float*)d_in[4];
  const float* b2 = (const float*)d_in[5];
  const float* W3 = (const float*)d_in[6];
  const float* b3 = (const float*)d_in[7];
  const float* W4 = (const float*)d_in[8];
  const float* b4 = (const float*)d_in[9];
  float* out = (float*)d_out;
  const int n = in_sizes[1];

  k_deepset<<<NSEG, 512, 0, stream>>>(x, xb, n, W1, b1, W2, b2, W3, b3, W4, b4, out);
}